// Round 7
// baseline (2176.064 us; speedup 1.0000x reference)
//
#include <hip/hip_runtime.h>

// ---------------------------------------------------------------------------
// Transformer (GateLoop-style) forward, MI355X/gfx950.  Round 7.
//  = round 6 (all-fp16 GEMMs, fused qkv|a|g, swizzled LDS) +
//  - minimum-2-phase GEMM pipeline (T3 recipe): double-buffered LDS, stage
//    tile t+1 BEFORE computing tile t, ONE __syncthreads per K-step (its
//    implicit vmcnt(0) drain covers loads that had a full compute phase to
//    land).  Replaces stage->drain->compute (2 barriers, no overlap).
//  - T1 bijective XCD-aware block swizzle (all GEMM grids divisible by 8):
//    blocks sharing a B-panel land on one XCD -> B fetched ~once from HBM.
// ---------------------------------------------------------------------------

typedef float fx4 __attribute__((ext_vector_type(4)));
typedef _Float16 f16x8 __attribute__((ext_vector_type(8)));
typedef _Float16 f16x4 __attribute__((ext_vector_type(4)));

#define AS1 __attribute__((address_space(1)))
#define AS3 __attribute__((address_space(3)))

// ---------------------------------------------------------------- transpose
// in: f32 [K][N] (batch z) -> fp16 [N][K] at out + z*ostride
__global__ __launch_bounds__(256) void transpose_f16_kernel(
    const float* __restrict__ in, _Float16* __restrict__ out,
    int K, int N, size_t ostride)
{
    __shared__ float tile[32][33];
    const int b = blockIdx.z;
    in  += (size_t)b * K * N;
    out += (size_t)b * ostride;
    const int k0 = blockIdx.x * 32, n0 = blockIdx.y * 32;
    const int tr = threadIdx.x >> 3;
    const int tc = (threadIdx.x & 7) * 4;
    fx4 v = *(const fx4*)&in[(size_t)(k0 + tr) * N + n0 + tc];
    tile[tr][tc + 0] = v[0]; tile[tr][tc + 1] = v[1];
    tile[tr][tc + 2] = v[2]; tile[tr][tc + 3] = v[3];
    __syncthreads();
    f16x4 o;
    #pragma unroll
    for (int e = 0; e < 4; ++e) o[e] = (_Float16)tile[tc + e][tr];
    *(f16x4*)&out[(size_t)(n0 + tr) * K + k0 + tc] = o;
}

// ---------------------------------------------------------------- embedding
__global__ __launch_bounds__(256) void embed_kernel(
    const int* __restrict__ tokens, const float* __restrict__ emb,
    float* __restrict__ x)
{
    const int row = blockIdx.x;
    const int t = tokens[row];
    const int c = threadIdx.x * 4;
    *(fx4*)&x[(size_t)row * 1024 + c] = *(const fx4*)&emb[(size_t)t * 1024 + c];
}

// ---------------------------------------------------------------- rms -> fp16
__global__ __launch_bounds__(256) void rms_f16_kernel(
    const float* __restrict__ x, const float* __restrict__ g,
    _Float16* __restrict__ outh)
{
    const int row = blockIdx.x;
    const int c = threadIdx.x * 4;
    fx4 v = *(const fx4*)&x[(size_t)row * 1024 + c];
    float ss = v[0]*v[0] + v[1]*v[1] + v[2]*v[2] + v[3]*v[3];
    #pragma unroll
    for (int off = 32; off > 0; off >>= 1) ss += __shfl_down(ss, off, 64);
    __shared__ float wsum[4];
    if ((threadIdx.x & 63) == 0) wsum[threadIdx.x >> 6] = ss;
    __syncthreads();
    const float nrm = sqrtf(wsum[0] + wsum[1] + wsum[2] + wsum[3]);
    const float scale = 32.0f / fmaxf(nrm, 1e-12f);
    fx4 gg = *(const fx4*)&g[c];
    f16x4 o;
    #pragma unroll
    for (int e = 0; e < 4; ++e) o[e] = (_Float16)(v[e] * scale * gg[e]);
    *(f16x4*)&outh[(size_t)row * 1024 + c] = o;
}

// ---------------------------------------------------------------- scan prep
// qkv [b][n][3072] -> qT[b*1024+h][n], kvT = k*v  (coalesced tiled transpose)
__global__ __launch_bounds__(256) void prep_qkv_kernel(
    const float* __restrict__ qkv, float* __restrict__ qT, float* __restrict__ kvT)
{
    __shared__ float tq[32][33], tkv[32][33];
    const int n0 = blockIdx.x * 32, h0 = blockIdx.y * 32, b = blockIdx.z;
    const int tr = threadIdx.x >> 3;
    const int tc = (threadIdx.x & 7) * 4;
    const float* row = qkv + ((size_t)b * 2048 + n0 + tr) * 3072;
    fx4 qv = *(const fx4*)&row[h0 + tc];
    fx4 kv = *(const fx4*)&row[1024 + h0 + tc];
    fx4 vv = *(const fx4*)&row[2048 + h0 + tc];
    #pragma unroll
    for (int e = 0; e < 4; ++e) { tq[tr][tc + e] = qv[e]; tkv[tr][tc + e] = kv[e] * vv[e]; }
    __syncthreads();
    fx4 oq, okv;
    #pragma unroll
    for (int e = 0; e < 4; ++e) { oq[e] = tq[tc + e][tr]; okv[e] = tkv[tc + e][tr]; }
    const size_t ob = ((size_t)b * 1024 + h0 + tr) * 2048 + n0 + tc;
    *(fx4*)&qT[ob] = oq;
    *(fx4*)&kvT[ob] = okv;
}

// al [b][n][2048] (re,im interleaved per h) -> polar -> aReT/aImT [b*1024+h][n]
__global__ __launch_bounds__(256) void prep_a_kernel(
    const float* __restrict__ al, float* __restrict__ aReT, float* __restrict__ aImT)
{
    __shared__ float tre[32][33], tim[32][33];
    const int n0 = blockIdx.x * 32, h0 = blockIdx.y * 32, b = blockIdx.z;
    const int tr = threadIdx.x >> 3;          // n offset
    const int tcf = (threadIdx.x & 7) * 8;    // float offset (covers 4 heads)
    const float* row = al + ((size_t)b * 2048 + n0 + tr) * 2048 + 2 * h0;
    fx4 v0 = *(const fx4*)&row[tcf];
    fx4 v1 = *(const fx4*)&row[tcf + 4];
    #pragma unroll
    for (int p = 0; p < 4; ++p) {
        float re = (p < 2) ? v0[2 * p] : v1[2 * (p - 2)];
        float im = (p < 2) ? v0[2 * p + 1] : v1[2 * (p - 2) + 1];
        float r = sqrtf(re * re + im * im);
        float sg = 1.0f / (1.0f + expf(-r));
        float a_re, a_im;
        if (r > 0.0f) { float inv = sg / r; a_re = re * inv; a_im = im * inv; }
        else          { a_re = sg; a_im = 0.0f; }
        tre[tr][tcf / 2 + p] = a_re;
        tim[tr][tcf / 2 + p] = a_im;
    }
    __syncthreads();
    const int tc = (threadIdx.x & 7) * 4;
    fx4 ore, oim;
    #pragma unroll
    for (int e = 0; e < 4; ++e) { ore[e] = tre[tc + e][tr]; oim[e] = tim[tc + e][tr]; }
    const size_t ob = ((size_t)b * 1024 + h0 + tr) * 2048 + n0 + tc;
    *(fx4*)&aReT[ob] = ore;
    *(fx4*)&aImT[ob] = oim;
}

// ---------------------------------------------------------------- gate-loop scan
// One block per (b,h), inputs/outputs transposed (fully coalesced).
// Brent-Kung == jax.lax.associative_scan bracketing (binop NON-associative).
__device__ __forceinline__ int pidx(int i) { return i + (i >> 5); }

__global__ __launch_bounds__(256) void scanT_kernel(
    const float* __restrict__ kvT, const float* __restrict__ aReT,
    const float* __restrict__ aImT, const float* __restrict__ qT,
    float* __restrict__ yT)
{
    const int tid = threadIdx.x;
    const size_t base = (size_t)blockIdx.x * 2048;
    __shared__ float s_re[2048 + 64], s_im[2048 + 64], s_kv[2048 + 64];

    for (int i = tid; i < 512; i += 256) {
        fx4 kv = *(const fx4*)&kvT[base + i * 4];
        fx4 re = *(const fx4*)&aReT[base + i * 4];
        fx4 im = *(const fx4*)&aImT[base + i * 4];
        #pragma unroll
        for (int e = 0; e < 4; ++e) {
            const int j = pidx(i * 4 + e);
            s_kv[j] = kv[e]; s_re[j] = re[e]; s_im[j] = im[e];
        }
    }
    __syncthreads();

    for (int d = 0; d < 11; ++d) {
        const int half = 1 << d, stride = half << 1;
        const int npairs = 2048 >> (d + 1);
        for (int i = tid; i < npairs; i += 256) {
            const int rj = pidx(i * stride + stride - 1);
            const int lj = pidx(i * stride + stride - 1 - half);
            float lre = s_re[lj], lim = s_im[lj], lkv = s_kv[lj];
            float rre = s_re[rj], rim = s_im[rj], rkv = s_kv[rj];
            s_kv[rj] = rre * lkv + rkv;
            s_re[rj] = rre * lre - rim * lim;
            s_im[rj] = rre * lim + rim * lre;
        }
        __syncthreads();
    }
    for (int d = 9; d >= 0; --d) {
        const int w = 1 << d;
        const int nupd = (2048 >> (d + 1)) - 1;
        for (int t = tid; t < nupd; t += 256) {
            const int i = t + 1;
            const int rj = pidx((2 * i + 1) * w - 1);
            const int lj = pidx(2 * i * w - 1);
            float lre = s_re[lj], lim = s_im[lj], lkv = s_kv[lj];
            float rre = s_re[rj], rim = s_im[rj], rkv = s_kv[rj];
            s_kv[rj] = rre * lkv + rkv;
            s_re[rj] = rre * lre - rim * lim;
            s_im[rj] = rre * lim + rim * lre;
        }
        __syncthreads();
    }
    for (int i = tid; i < 512; i += 256) {
        fx4 q = *(const fx4*)&qT[base + i * 4];
        fx4 o;
        #pragma unroll
        for (int e = 0; e < 4; ++e) o[e] = q[e] * s_kv[pidx(i * 4 + e)];
        *(fx4*)&yT[base + i * 4] = o;
    }
}

// ---------------------------------------------------------------- gating
// gated[n][h] = fp16( silu(G[n][h]) * y[h][n] )   (y transposed via LDS tile)
__global__ __launch_bounds__(256) void gate_kernel(
    const float* __restrict__ G, const float* __restrict__ yT,
    _Float16* __restrict__ gated)
{
    __shared__ float ty[32][33];
    const int n0 = blockIdx.x * 32, h0 = blockIdx.y * 32, b = blockIdx.z;
    const int tr = threadIdx.x >> 3;
    const int tc = (threadIdx.x & 7) * 4;
    fx4 yv = *(const fx4*)&yT[((size_t)b * 1024 + h0 + tr) * 2048 + n0 + tc];
    #pragma unroll
    for (int e = 0; e < 4; ++e) ty[tr][tc + e] = yv[e];
    __syncthreads();
    const size_t grow = ((size_t)b * 2048 + n0 + tr) * 1024 + h0 + tc;
    fx4 gv = *(const fx4*)&G[grow];
    f16x4 o;
    #pragma unroll
    for (int e = 0; e < 4; ++e) {
        const float s = gv[e] / (1.0f + expf(-gv[e]));   // silu
        o[e] = (_Float16)(s * ty[tc + e][tr]);
    }
    *(f16x4*)&gated[grow] = o;
}

// ---------------------------------------------------------------- GEMM (fp16)
// C[M,N] = A[M,K](fp16) * Bt[N,K]^T(fp16), f32 accumulate.
// Minimum-2-phase pipeline: dbuf LDS; STAGE(t+1) issued BEFORE compute(t);
// one __syncthreads per K-step (implicit vmcnt(0) covers the stage that had
// a full compute phase in flight).  LDS XOR swizzle (16B granules, involution
// on source + ds_read; verified: conflicts -> 0).  T1 bijective XCD swizzle.
// EPI: 0=store f32, 2=Cf+=v, 3=Cf+=v+bias, 4=Ch=f16(gelu(v+bias)),
//      6=fused routing: bn<24 -> Cf(qkv, ld 3072); bn<40 -> Cf2+bias(al, ld
//        2048, bias idx col-3072); else Cf3(G, ld 1024)
template<int EPI>
__global__ __launch_bounds__(256) void gemm_kernel(
    const _Float16* __restrict__ A, const _Float16* __restrict__ Bt,
    const float* __restrict__ bias,
    float* __restrict__ Cf, float* __restrict__ Cf2, float* __restrict__ Cf3,
    _Float16* __restrict__ Ch,
    int M, int N, int K)
{
    __shared__ __align__(16) _Float16 As[2][128 * 64];
    __shared__ __align__(16) _Float16 Bs[2][128 * 64];
    const int tid  = threadIdx.x;
    const int lane = tid & 63;
    const int wave = tid >> 6;

    // T1: bijective XCD-aware remap (all grids here are divisible by 8)
    const int nwgx = gridDim.x;
    const int nwg  = nwgx * gridDim.y;
    const int g    = blockIdx.y * nwgx + blockIdx.x;
    const int g2   = (g % 8) * (nwg >> 3) + (g >> 3);
    const int bm   = g2 % nwgx;
    const int bn   = g2 / nwgx;

    const int wm = (wave >> 1) * 64, wn = (wave & 1) * 64;

    fx4 acc[4][4] = {};

    const size_t aRow0 = (size_t)bm * 128;
    const size_t bRow0 = (size_t)bn * 128;

    // staging: 256 threads x 4 chunks x 16B per operand tile (128x64 fp16)
    const int s_row  = (tid * 8 + 0) >> 3;  // placeholder to keep naming clear
    (void)s_row;

    auto stage = [&](int buf, int k0) {
        #pragma unroll
        for (int q = 0; q < 4; ++q) {
            const int chunk = q * 256 + tid;          // 0..1023
            const int row = chunk >> 3;               // 0..127
            const int slot = chunk & 7;
            const int gs = slot ^ (row & 7);          // pre-swizzled source slot
            const size_t aoff = (aRow0 + row) * K + k0 + gs * 8;
            const size_t boff = (bRow0 + row) * K + k0 + gs * 8;
            __builtin_amdgcn_global_load_lds((const AS1 void*)(A + aoff),
                (AS3 void*)((char*)&As[buf][0] + chunk * 16), 16, 0, 0);
            __builtin_amdgcn_global_load_lds((const AS1 void*)(Bt + boff),
                (AS3 void*)((char*)&Bs[buf][0] + chunk * 16), 16, 0, 0);
        }
    };

    stage(0, 0);
    __syncthreads();   // drain prologue stage

    int buf = 0;
    for (int k0 = 0; k0 < K; k0 += 64, buf ^= 1) {
        if (k0 + 64 < K) stage(buf ^ 1, k0 + 64);   // overlap with compute(t)

        #pragma unroll
        for (int kk = 0; kk < 2; ++kk) {
            const int sw = ((kk * 4 + (lane >> 4)) ^ (lane & 7)) * 16;
            f16x8 af[4], bf[4];
            #pragma unroll
            for (int i = 0; i < 4; ++i) {
                const int row = wm + i * 16 + (lane & 15);
                af[i] = *(const f16x8*)((const char*)&As[buf][0] + row * 128 + sw);
            }
            #pragma unroll
            for (int j = 0; j < 4; ++j) {
                const int row = wn + j * 16 + (lane & 15);
                bf[j] = *(const f16x8*)((const char*)&Bs[buf][0] + row * 128 + sw);
            }
            #pragma unroll
            for (int i = 0; i < 4; ++i)
                #pragma unroll
                for (int j = 0; j < 4; ++j)
                    acc[i][j] = __builtin_amdgcn_mfma_f32_16x16x32_f16(
                        af[i], bf[j], acc[i][j], 0, 0, 0);
        }
        __syncthreads();  // waves joined + next-tile stage drained (vmcnt 0)
    }

    // epilogue: C/D layout col=lane&15, row=(lane>>4)*4+r
    const int col_l = lane & 15, row_l = (lane >> 4) * 4;
    #pragma unroll
    for (int i = 0; i < 4; ++i) {
        #pragma unroll
        for (int j = 0; j < 4; ++j) {
            #pragma unroll
            for (int r = 0; r < 4; ++r) {
                const int row = bm * 128 + wm + i * 16 + row_l + r;
                const int col = bn * 128 + wn + j * 16 + col_l;
                const float v = acc[i][j][r];
                if (EPI == 0) {
                    Cf[(size_t)row * N + col] = v;
                } else if (EPI == 2) {
                    Cf[(size_t)row * N + col] += v;
                } else if (EPI == 3) {
                    Cf[(size_t)row * N + col] += v + bias[col];
                } else if (EPI == 4) {
                    const float t = v + bias[col];
                    const float gelu = 0.5f * t * (1.0f + erff(t * 0.70710678118654752f));
                    Ch[(size_t)row * N + col] = (_Float16)gelu;
                } else if (EPI == 6) {
                    if (bn < 24)      Cf [(size_t)row * 3072 + col] = v;
                    else if (bn < 40) Cf2[(size_t)row * 2048 + (col - 3072)] = v + bias[col - 3072];
                    else              Cf3[(size_t)row * 1024 + (col - 5120)] = v;
                }
            }
        }
    }
}

// ---------------------------------------------------------------- host
extern "C" void kernel_launch(void* const* d_in, const int* in_sizes, int n_in,
                              void* d_out, int out_size, void* d_ws, size_t ws_size,
                              hipStream_t stream)
{
    const int*   tokens = (const int*)d_in[0];
    const float* emb  = (const float*)d_in[1];
    const float* g1   = (const float*)d_in[2];
    const float* Wqkv = (const float*)d_in[3];
    const float* Wa   = (const float*)d_in[4];
    const float* ba   = (const float*)d_in[5];
    const float* Wg   = (const float*)d_in[6];
    const float* Wo   = (const float*)d_in[7];
    const float* g2   = (const float*)d_in[8];
    const float* W1   = (const float*)d_in[9];
    const float* b1   = (const float*)d_in[10];
    const float* W2   = (const float*)d_in[11];
    const float* b2   = (const float*)d_in[12];
    const float* gf   = (const float*)d_in[13];
    const float* Wl   = (const float*)d_in[14];
    float* out = (float*)d_out;

    char* ws = (char*)d_ws;
    size_t off = 0;
    auto take = [&](size_t bytes) {
        char* p = ws + off; off += (bytes + 255) & ~(size_t)255; return p;
    };

    // fp16 weights
    _Float16* wcat = (_Float16*)take((size_t)4 * 6144 * 1024 * 2);   // [Wqkv|Wa|Wg]^T per layer
    _Float16* wo   = (_Float16*)take((size_t)4 * 1024 * 1024 * 2);
    _Float16* w1   = (_Float16*)take((size_t)4 * 4096 * 1024 * 2);
    _Float16* w2   = (_Float16*)take((size_t)4 * 1024 * 4096 * 2);
    // region shared by 4x16MiB scan scratch (layers) and Wl fp16 (62.5MiB, end)
    char*     wlRegion = take((size_t)64 << 20);
    _Float16* wl   = (_Float16*)wlRegion;
    float*    x    = (float*)take((size_t)4096 * 1024 * 4);
    _Float16* xn   = (_Float16*)take((size_t)4096 * 1024 * 2);
    float*    qkvb = (float*)take((size_t)4096 * 3072 * 4);   // 48MiB (also hosts h fp16 33.5MiB)
    float*    alb  = (float*)take((size_t)4096 * 2048 * 4);   // 32MiB (also yT + gated)
    float*    G    = (float*)take((size_t)4096 * 1024 * 4);   // 16MiB

    float* qT   = (float*)wlRegion;
    float* kvT  = (float*)(wlRegion + ((size_t)16 << 20));
    float* aReT = (float*)(wlRegion + ((size_t)32 << 20));
    float* aImT = (float*)(wlRegion + ((size_t)48 << 20));
    float*    yT    = alb;                                           // [0,16MiB)
    _Float16* gated = (_Float16*)((char*)alb + ((size_t)16 << 20));  // 8.4MiB
    _Float16* h     = (_Float16*)qkvb;                               // 33.5MiB

    const dim3 blk(256);

    // weight transposes (f32 [K][N] -> fp16 [N][K])
    transpose_f16_kernel<<<dim3(32,  96, 4), blk, 0, stream>>>(Wqkv, wcat,               1024, 3072, (size_t)6144 * 1024);
    transpose_f16_kernel<<<dim3(32,  64, 4), blk, 0, stream>>>(Wa,   wcat + 3072 * 1024, 1024, 2048, (size_t)6144 * 1024);
    transpose_f16_kernel<<<dim3(32,  32, 4), blk, 0, stream>>>(Wg,   wcat + 5120 * 1024, 1024, 1024, (size_t)6144 * 1024);
    transpose_f16_kernel<<<dim3(32,  32, 4), blk, 0, stream>>>(Wo,   wo,  1024, 1024, (size_t)1024 * 1024);
    transpose_f16_kernel<<<dim3(32, 128, 4), blk, 0, stream>>>(W1,   w1,  1024, 4096, (size_t)4096 * 1024);
    transpose_f16_kernel<<<dim3(128, 32, 4), blk, 0, stream>>>(W2,   w2,  4096, 1024, (size_t)1024 * 4096);

    embed_kernel<<<4096, blk, 0, stream>>>(tokens, emb, x);

    for (int i = 0; i < 4; ++i) {
        rms_f16_kernel<<<4096, blk, 0, stream>>>(x, g1 + i * 1024, xn);
        gemm_kernel<6><<<dim3(32, 48), blk, 0, stream>>>(
            xn, wcat + (size_t)i * 6144 * 1024, ba + i * 2048,
            qkvb, alb, G, nullptr, 4096, 6144, 1024);
        prep_qkv_kernel<<<dim3(64, 32, 2), blk, 0, stream>>>(qkvb, qT, kvT);
        prep_a_kernel<<<dim3(64, 32, 2), blk, 0, stream>>>(alb, aReT, aImT);
        scanT_kernel<<<2048, blk, 0, stream>>>(kvT, aReT, aImT, qT, yT);
        gate_kernel<<<dim3(64, 32, 2), blk, 0, stream>>>(G, yT, gated);
        gemm_kernel<2><<<dim3(32, 8), blk, 0, stream>>>(
            gated, wo + (size_t)i * 1024 * 1024, nullptr,
            x, nullptr, nullptr, nullptr, 4096, 1024, 1024);
        rms_f16_kernel<<<4096, blk, 0, stream>>>(x, g2 + i * 1024, xn);
        gemm_kernel<4><<<dim3(32, 32), blk, 0, stream>>>(
            xn, w1 + (size_t)i * 4096 * 1024, b1 + i * 4096,
            nullptr, nullptr, nullptr, h, 4096, 4096, 1024);
        gemm_kernel<3><<<dim3(32, 8), blk, 0, stream>>>(
            h, w2 + (size_t)i * 1024 * 4096, b2 + i * 1024,
            x, nullptr, nullptr, nullptr, 4096, 1024, 4096);
    }

    // Wl transpose deferred: its region was scan scratch during the layers
    transpose_f16_kernel<<<dim3(32, 1000, 1), blk, 0, stream>>>(Wl, wl, 1024, 32000, 0);

    rms_f16_kernel<<<4096, blk, 0, stream>>>(x, gf, xn);
    gemm_kernel<0><<<dim3(32, 250), blk, 0, stream>>>(
        xn, wl, nullptr, out, nullptr, nullptr, nullptr, 4096, 32000, 1024);
}

// Round 8
// 1837.790 us; speedup vs baseline: 1.1841x; 1.1841x over previous
//
#include <hip/hip_runtime.h>

// ---------------------------------------------------------------------------
// Transformer (GateLoop-style) forward, MI355X/gfx950.  Round 8.
//  = round 6 (all-fp16 GEMMs, fused qkv|a|g, swizzled LDS, NO xcd swizzle,
//    NO dbuf — both reverted after round-7 regression) with the GEMM block
//    tile enlarged: BM=256 x BN=128, 8 waves (512 thr), wave tile 64x64.
//    Rationale: rounds 5/6/7 show ~fixed per-K-step latency cost dominating;
//    2x per-block work amortizes it (same proven 2-barrier sync structure).
// ---------------------------------------------------------------------------

typedef float fx4 __attribute__((ext_vector_type(4)));
typedef _Float16 f16x8 __attribute__((ext_vector_type(8)));
typedef _Float16 f16x4 __attribute__((ext_vector_type(4)));

#define AS1 __attribute__((address_space(1)))
#define AS3 __attribute__((address_space(3)))

// ---------------------------------------------------------------- transpose
// in: f32 [K][N] (batch z) -> fp16 [N][K] at out + z*ostride
__global__ __launch_bounds__(256) void transpose_f16_kernel(
    const float* __restrict__ in, _Float16* __restrict__ out,
    int K, int N, size_t ostride)
{
    __shared__ float tile[32][33];
    const int b = blockIdx.z;
    in  += (size_t)b * K * N;
    out += (size_t)b * ostride;
    const int k0 = blockIdx.x * 32, n0 = blockIdx.y * 32;
    const int tr = threadIdx.x >> 3;
    const int tc = (threadIdx.x & 7) * 4;
    fx4 v = *(const fx4*)&in[(size_t)(k0 + tr) * N + n0 + tc];
    tile[tr][tc + 0] = v[0]; tile[tr][tc + 1] = v[1];
    tile[tr][tc + 2] = v[2]; tile[tr][tc + 3] = v[3];
    __syncthreads();
    f16x4 o;
    #pragma unroll
    for (int e = 0; e < 4; ++e) o[e] = (_Float16)tile[tc + e][tr];
    *(f16x4*)&out[(size_t)(n0 + tr) * K + k0 + tc] = o;
}

// ---------------------------------------------------------------- embedding
__global__ __launch_bounds__(256) void embed_kernel(
    const int* __restrict__ tokens, const float* __restrict__ emb,
    float* __restrict__ x)
{
    const int row = blockIdx.x;
    const int t = tokens[row];
    const int c = threadIdx.x * 4;
    *(fx4*)&x[(size_t)row * 1024 + c] = *(const fx4*)&emb[(size_t)t * 1024 + c];
}

// ---------------------------------------------------------------- rms -> fp16
__global__ __launch_bounds__(256) void rms_f16_kernel(
    const float* __restrict__ x, const float* __restrict__ g,
    _Float16* __restrict__ outh)
{
    const int row = blockIdx.x;
    const int c = threadIdx.x * 4;
    fx4 v = *(const fx4*)&x[(size_t)row * 1024 + c];
    float ss = v[0]*v[0] + v[1]*v[1] + v[2]*v[2] + v[3]*v[3];
    #pragma unroll
    for (int off = 32; off > 0; off >>= 1) ss += __shfl_down(ss, off, 64);
    __shared__ float wsum[4];
    if ((threadIdx.x & 63) == 0) wsum[threadIdx.x >> 6] = ss;
    __syncthreads();
    const float nrm = sqrtf(wsum[0] + wsum[1] + wsum[2] + wsum[3]);
    const float scale = 32.0f / fmaxf(nrm, 1e-12f);
    fx4 gg = *(const fx4*)&g[c];
    f16x4 o;
    #pragma unroll
    for (int e = 0; e < 4; ++e) o[e] = (_Float16)(v[e] * scale * gg[e]);
    *(f16x4*)&outh[(size_t)row * 1024 + c] = o;
}

// ---------------------------------------------------------------- scan prep
// qkv [b][n][3072] -> qT[b*1024+h][n], kvT = k*v  (coalesced tiled transpose)
__global__ __launch_bounds__(256) void prep_qkv_kernel(
    const float* __restrict__ qkv, float* __restrict__ qT, float* __restrict__ kvT)
{
    __shared__ float tq[32][33], tkv[32][33];
    const int n0 = blockIdx.x * 32, h0 = blockIdx.y * 32, b = blockIdx.z;
    const int tr = threadIdx.x >> 3;
    const int tc = (threadIdx.x & 7) * 4;
    const float* row = qkv + ((size_t)b * 2048 + n0 + tr) * 3072;
    fx4 qv = *(const fx4*)&row[h0 + tc];
    fx4 kv = *(const fx4*)&row[1024 + h0 + tc];
    fx4 vv = *(const fx4*)&row[2048 + h0 + tc];
    #pragma unroll
    for (int e = 0; e < 4; ++e) { tq[tr][tc + e] = qv[e]; tkv[tr][tc + e] = kv[e] * vv[e]; }
    __syncthreads();
    fx4 oq, okv;
    #pragma unroll
    for (int e = 0; e < 4; ++e) { oq[e] = tq[tc + e][tr]; okv[e] = tkv[tc + e][tr]; }
    const size_t ob = ((size_t)b * 1024 + h0 + tr) * 2048 + n0 + tc;
    *(fx4*)&qT[ob] = oq;
    *(fx4*)&kvT[ob] = okv;
}

// al [b][n][2048] (re,im interleaved per h) -> polar -> aReT/aImT [b*1024+h][n]
__global__ __launch_bounds__(256) void prep_a_kernel(
    const float* __restrict__ al, float* __restrict__ aReT, float* __restrict__ aImT)
{
    __shared__ float tre[32][33], tim[32][33];
    const int n0 = blockIdx.x * 32, h0 = blockIdx.y * 32, b = blockIdx.z;
    const int tr = threadIdx.x >> 3;          // n offset
    const int tcf = (threadIdx.x & 7) * 8;    // float offset (covers 4 heads)
    const float* row = al + ((size_t)b * 2048 + n0 + tr) * 2048 + 2 * h0;
    fx4 v0 = *(const fx4*)&row[tcf];
    fx4 v1 = *(const fx4*)&row[tcf + 4];
    #pragma unroll
    for (int p = 0; p < 4; ++p) {
        float re = (p < 2) ? v0[2 * p] : v1[2 * (p - 2)];
        float im = (p < 2) ? v0[2 * p + 1] : v1[2 * (p - 2) + 1];
        float r = sqrtf(re * re + im * im);
        float sg = 1.0f / (1.0f + expf(-r));
        float a_re, a_im;
        if (r > 0.0f) { float inv = sg / r; a_re = re * inv; a_im = im * inv; }
        else          { a_re = sg; a_im = 0.0f; }
        tre[tr][tcf / 2 + p] = a_re;
        tim[tr][tcf / 2 + p] = a_im;
    }
    __syncthreads();
    const int tc = (threadIdx.x & 7) * 4;
    fx4 ore, oim;
    #pragma unroll
    for (int e = 0; e < 4; ++e) { ore[e] = tre[tc + e][tr]; oim[e] = tim[tc + e][tr]; }
    const size_t ob = ((size_t)b * 1024 + h0 + tr) * 2048 + n0 + tc;
    *(fx4*)&aReT[ob] = ore;
    *(fx4*)&aImT[ob] = oim;
}

// ---------------------------------------------------------------- gate-loop scan
// One block per (b,h), inputs/outputs transposed (fully coalesced).
// Brent-Kung == jax.lax.associative_scan bracketing (binop NON-associative).
__device__ __forceinline__ int pidx(int i) { return i + (i >> 5); }

__global__ __launch_bounds__(256) void scanT_kernel(
    const float* __restrict__ kvT, const float* __restrict__ aReT,
    const float* __restrict__ aImT, const float* __restrict__ qT,
    float* __restrict__ yT)
{
    const int tid = threadIdx.x;
    const size_t base = (size_t)blockIdx.x * 2048;
    __shared__ float s_re[2048 + 64], s_im[2048 + 64], s_kv[2048 + 64];

    for (int i = tid; i < 512; i += 256) {
        fx4 kv = *(const fx4*)&kvT[base + i * 4];
        fx4 re = *(const fx4*)&aReT[base + i * 4];
        fx4 im = *(const fx4*)&aImT[base + i * 4];
        #pragma unroll
        for (int e = 0; e < 4; ++e) {
            const int j = pidx(i * 4 + e);
            s_kv[j] = kv[e]; s_re[j] = re[e]; s_im[j] = im[e];
        }
    }
    __syncthreads();

    for (int d = 0; d < 11; ++d) {
        const int half = 1 << d, stride = half << 1;
        const int npairs = 2048 >> (d + 1);
        for (int i = tid; i < npairs; i += 256) {
            const int rj = pidx(i * stride + stride - 1);
            const int lj = pidx(i * stride + stride - 1 - half);
            float lre = s_re[lj], lim = s_im[lj], lkv = s_kv[lj];
            float rre = s_re[rj], rim = s_im[rj], rkv = s_kv[rj];
            s_kv[rj] = rre * lkv + rkv;
            s_re[rj] = rre * lre - rim * lim;
            s_im[rj] = rre * lim + rim * lre;
        }
        __syncthreads();
    }
    for (int d = 9; d >= 0; --d) {
        const int w = 1 << d;
        const int nupd = (2048 >> (d + 1)) - 1;
        for (int t = tid; t < nupd; t += 256) {
            const int i = t + 1;
            const int rj = pidx((2 * i + 1) * w - 1);
            const int lj = pidx(2 * i * w - 1);
            float lre = s_re[lj], lim = s_im[lj], lkv = s_kv[lj];
            float rre = s_re[rj], rim = s_im[rj], rkv = s_kv[rj];
            s_kv[rj] = rre * lkv + rkv;
            s_re[rj] = rre * lre - rim * lim;
            s_im[rj] = rre * lim + rim * lre;
        }
        __syncthreads();
    }
    for (int i = tid; i < 512; i += 256) {
        fx4 q = *(const fx4*)&qT[base + i * 4];
        fx4 o;
        #pragma unroll
        for (int e = 0; e < 4; ++e) o[e] = q[e] * s_kv[pidx(i * 4 + e)];
        *(fx4*)&yT[base + i * 4] = o;
    }
}

// ---------------------------------------------------------------- gating
// gated[n][h] = fp16( silu(G[n][h]) * y[h][n] )   (y transposed via LDS tile)
__global__ __launch_bounds__(256) void gate_kernel(
    const float* __restrict__ G, const float* __restrict__ yT,
    _Float16* __restrict__ gated)
{
    __shared__ float ty[32][33];
    const int n0 = blockIdx.x * 32, h0 = blockIdx.y * 32, b = blockIdx.z;
    const int tr = threadIdx.x >> 3;
    const int tc = (threadIdx.x & 7) * 4;
    fx4 yv = *(const fx4*)&yT[((size_t)b * 1024 + h0 + tr) * 2048 + n0 + tc];
    #pragma unroll
    for (int e = 0; e < 4; ++e) ty[tr][tc + e] = yv[e];
    __syncthreads();
    const size_t grow = ((size_t)b * 2048 + n0 + tr) * 1024 + h0 + tc;
    fx4 gv = *(const fx4*)&G[grow];
    f16x4 o;
    #pragma unroll
    for (int e = 0; e < 4; ++e) {
        const float s = gv[e] / (1.0f + expf(-gv[e]));   // silu
        o[e] = (_Float16)(s * ty[tc + e][tr]);
    }
    *(f16x4*)&gated[grow] = o;
}

// ---------------------------------------------------------------- GEMM (fp16)
// C[M,N] = A[M,K](fp16) * Bt[N,K]^T(fp16), f32 accumulate.
// Block tile 256x128, 8 waves (512 thr), wave tile 64x64 (4x4 fp32x4 acc).
// Single-buffer LDS (48 KB -> 3 LDS-blocks/CU), 2-barrier K-loop (proven).
// LDS XOR swizzle on 16B granules (involution on source + ds_read;
// verified round 5/6: SQ_LDS_BANK_CONFLICT == 0).
// EPI: 0=store f32, 2=Cf+=v, 3=Cf+=v+bias, 4=Ch=f16(gelu(v+bias)),
//      6=fused routing: bn<24 -> Cf(qkv, ld 3072); bn<40 -> Cf2+bias(al, ld
//        2048, bias idx col-3072); else Cf3(G, ld 1024)
template<int EPI>
__global__ __launch_bounds__(512) void gemm_kernel(
    const _Float16* __restrict__ A, const _Float16* __restrict__ Bt,
    const float* __restrict__ bias,
    float* __restrict__ Cf, float* __restrict__ Cf2, float* __restrict__ Cf3,
    _Float16* __restrict__ Ch,
    int M, int N, int K)
{
    __shared__ __align__(16) _Float16 As[256 * 64];   // 32 KB
    __shared__ __align__(16) _Float16 Bs[128 * 64];   // 16 KB
    const int tid  = threadIdx.x;
    const int lane = tid & 63;
    const int wave = tid >> 6;                        // 0..7
    const int bm = blockIdx.x, bn = blockIdx.y;
    const int wm = (wave >> 1) * 64;                  // 0,64,128,192
    const int wn = (wave & 1) * 64;                   // 0,64

    fx4 acc[4][4] = {};

    const size_t aRow0 = (size_t)bm * 256;
    const size_t bRow0 = (size_t)bn * 128;

    for (int k0 = 0; k0 < K; k0 += 64) {
        // stage A: 256 rows x 64 k = 2048 chunks of 16B; 512 thr -> 4 each
        #pragma unroll
        for (int q = 0; q < 4; ++q) {
            const int chunk = q * 512 + tid;          // 0..2047
            const int row = chunk >> 3;               // 0..255
            const int slot = chunk & 7;
            const int gs = slot ^ (row & 7);          // pre-swizzled source slot
            const size_t aoff = (aRow0 + row) * K + k0 + gs * 8;
            __builtin_amdgcn_global_load_lds((const AS1 void*)(A + aoff),
                (AS3 void*)((char*)As + chunk * 16), 16, 0, 0);
        }
        // stage B: 128 rows x 64 k = 1024 chunks; 2 each
        #pragma unroll
        for (int q = 0; q < 2; ++q) {
            const int chunk = q * 512 + tid;          // 0..1023
            const int row = chunk >> 3;               // 0..127
            const int slot = chunk & 7;
            const int gs = slot ^ (row & 7);
            const size_t boff = (bRow0 + row) * K + k0 + gs * 8;
            __builtin_amdgcn_global_load_lds((const AS1 void*)(Bt + boff),
                (AS3 void*)((char*)Bs + chunk * 16), 16, 0, 0);
        }
        __syncthreads();   // drains vmcnt(0): staged data visible

        #pragma unroll
        for (int kk = 0; kk < 2; ++kk) {
            // granule index XOR row&7; frag rows ≡ lane&7 (mod 8) for both ops
            const int sw = ((kk * 4 + (lane >> 4)) ^ (lane & 7)) * 16;
            f16x8 af[4], bf[4];
            #pragma unroll
            for (int i = 0; i < 4; ++i) {
                const int row = wm + i * 16 + (lane & 15);
                af[i] = *(const f16x8*)((const char*)As + row * 128 + sw);
            }
            #pragma unroll
            for (int j = 0; j < 4; ++j) {
                const int row = wn + j * 16 + (lane & 15);
                bf[j] = *(const f16x8*)((const char*)Bs + row * 128 + sw);
            }
            #pragma unroll
            for (int i = 0; i < 4; ++i)
                #pragma unroll
                for (int j = 0; j < 4; ++j)
                    acc[i][j] = __builtin_amdgcn_mfma_f32_16x16x32_f16(
                        af[i], bf[j], acc[i][j], 0, 0, 0);
        }
        __syncthreads();   // all reads done before next staging overwrites
    }

    // epilogue: C/D layout col=lane&15, row=(lane>>4)*4+r
    const int col_l = lane & 15, row_l = (lane >> 4) * 4;
    #pragma unroll
    for (int i = 0; i < 4; ++i) {
        #pragma unroll
        for (int j = 0; j < 4; ++j) {
            #pragma unroll
            for (int r = 0; r < 4; ++r) {
                const int row = bm * 256 + wm + i * 16 + row_l + r;
                const int col = bn * 128 + wn + j * 16 + col_l;
                const float v = acc[i][j][r];
                if (EPI == 0) {
                    Cf[(size_t)row * N + col] = v;
                } else if (EPI == 2) {
                    Cf[(size_t)row * N + col] += v;
                } else if (EPI == 3) {
                    Cf[(size_t)row * N + col] += v + bias[col];
                } else if (EPI == 4) {
                    const float t = v + bias[col];
                    const float gelu = 0.5f * t * (1.0f + erff(t * 0.70710678118654752f));
                    Ch[(size_t)row * N + col] = (_Float16)gelu;
                } else if (EPI == 6) {
                    if (bn < 24)      Cf [(size_t)row * 3072 + col] = v;
                    else if (bn < 40) Cf2[(size_t)row * 2048 + (col - 3072)] = v + bias[col - 3072];
                    else              Cf3[(size_t)row * 1024 + (col - 5120)] = v;
                }
            }
        }
    }
}

// ---------------------------------------------------------------- host
extern "C" void kernel_launch(void* const* d_in, const int* in_sizes, int n_in,
                              void* d_out, int out_size, void* d_ws, size_t ws_size,
                              hipStream_t stream)
{
    const int*   tokens = (const int*)d_in[0];
    const float* emb  = (const float*)d_in[1];
    const float* g1   = (const float*)d_in[2];
    const float* Wqkv = (const float*)d_in[3];
    const float* Wa   = (const float*)d_in[4];
    const float* ba   = (const float*)d_in[5];
    const float* Wg   = (const float*)d_in[6];
    const float* Wo   = (const float*)d_in[7];
    const float* g2   = (const float*)d_in[8];
    const float* W1   = (const float*)d_in[9];
    const float* b1   = (const float*)d_in[10];
    const float* W2   = (const float*)d_in[11];
    const float* b2   = (const float*)d_in[12];
    const float* gf   = (const float*)d_in[13];
    const float* Wl   = (const float*)d_in[14];
    float* out = (float*)d_out;

    char* ws = (char*)d_ws;
    size_t off = 0;
    auto take = [&](size_t bytes) {
        char* p = ws + off; off += (bytes + 255) & ~(size_t)255; return p;
    };

    // fp16 weights
    _Float16* wcat = (_Float16*)take((size_t)4 * 6144 * 1024 * 2);   // [Wqkv|Wa|Wg]^T per layer
    _Float16* wo   = (_Float16*)take((size_t)4 * 1024 * 1024 * 2);
    _Float16* w1   = (_Float16*)take((size_t)4 * 4096 * 1024 * 2);
    _Float16* w2   = (_Float16*)take((size_t)4 * 1024 * 4096 * 2);
    // region shared by 4x16MiB scan scratch (layers) and Wl fp16 (62.5MiB, end)
    char*     wlRegion = take((size_t)64 << 20);
    _Float16* wl   = (_Float16*)wlRegion;
    float*    x    = (float*)take((size_t)4096 * 1024 * 4);
    _Float16* xn   = (_Float16*)take((size_t)4096 * 1024 * 2);
    float*    qkvb = (float*)take((size_t)4096 * 3072 * 4);   // 48MiB (also hosts h fp16 33.5MiB)
    float*    alb  = (float*)take((size_t)4096 * 2048 * 4);   // 32MiB (also yT + gated)
    float*    G    = (float*)take((size_t)4096 * 1024 * 4);   // 16MiB

    float* qT   = (float*)wlRegion;
    float* kvT  = (float*)(wlRegion + ((size_t)16 << 20));
    float* aReT = (float*)(wlRegion + ((size_t)32 << 20));
    float* aImT = (float*)(wlRegion + ((size_t)48 << 20));
    float*    yT    = alb;                                           // [0,16MiB)
    _Float16* gated = (_Float16*)((char*)alb + ((size_t)16 << 20));  // 8.4MiB
    _Float16* h     = (_Float16*)qkvb;                               // 33.5MiB

    const dim3 blk(256);
    const dim3 gblk(512);

    // weight transposes (f32 [K][N] -> fp16 [N][K])
    transpose_f16_kernel<<<dim3(32,  96, 4), blk, 0, stream>>>(Wqkv, wcat,               1024, 3072, (size_t)6144 * 1024);
    transpose_f16_kernel<<<dim3(32,  64, 4), blk, 0, stream>>>(Wa,   wcat + 3072 * 1024, 1024, 2048, (size_t)6144 * 1024);
    transpose_f16_kernel<<<dim3(32,  32, 4), blk, 0, stream>>>(Wg,   wcat + 5120 * 1024, 1024, 1024, (size_t)6144 * 1024);
    transpose_f16_kernel<<<dim3(32,  32, 4), blk, 0, stream>>>(Wo,   wo,  1024, 1024, (size_t)1024 * 1024);
    transpose_f16_kernel<<<dim3(32, 128, 4), blk, 0, stream>>>(W1,   w1,  1024, 4096, (size_t)4096 * 1024);
    transpose_f16_kernel<<<dim3(128, 32, 4), blk, 0, stream>>>(W2,   w2,  4096, 1024, (size_t)1024 * 4096);

    embed_kernel<<<4096, blk, 0, stream>>>(tokens, emb, x);

    for (int i = 0; i < 4; ++i) {
        rms_f16_kernel<<<4096, blk, 0, stream>>>(x, g1 + i * 1024, xn);
        gemm_kernel<6><<<dim3(16, 48), gblk, 0, stream>>>(
            xn, wcat + (size_t)i * 6144 * 1024, ba + i * 2048,
            qkvb, alb, G, nullptr, 4096, 6144, 1024);
        prep_qkv_kernel<<<dim3(64, 32, 2), blk, 0, stream>>>(qkvb, qT, kvT);
        prep_a_kernel<<<dim3(64, 32, 2), blk, 0, stream>>>(alb, aReT, aImT);
        scanT_kernel<<<2048, blk, 0, stream>>>(kvT, aReT, aImT, qT, yT);
        gate_kernel<<<dim3(64, 32, 2), blk, 0, stream>>>(G, yT, gated);
        gemm_kernel<2><<<dim3(16, 8), gblk, 0, stream>>>(
            gated, wo + (size_t)i * 1024 * 1024, nullptr,
            x, nullptr, nullptr, nullptr, 4096, 1024, 1024);
        rms_f16_kernel<<<4096, blk, 0, stream>>>(x, g2 + i * 1024, xn);
        gemm_kernel<4><<<dim3(16, 32), gblk, 0, stream>>>(
            xn, w1 + (size_t)i * 4096 * 1024, b1 + i * 4096,
            nullptr, nullptr, nullptr, h, 4096, 4096, 1024);
        gemm_kernel<3><<<dim3(16, 8), gblk, 0, stream>>>(
            h, w2 + (size_t)i * 1024 * 4096, b2 + i * 1024,
            x, nullptr, nullptr, nullptr, 4096, 1024, 4096);
    }

    // Wl transpose deferred: its region was scan scratch during the layers
    transpose_f16_kernel<<<dim3(32, 1000, 1), blk, 0, stream>>>(Wl, wl, 1024, 32000, 0);

    rms_f16_kernel<<<4096, blk, 0, stream>>>(x, gf, xn);
    gemm_kernel<0><<<dim3(16, 250), gblk, 0, stream>>>(
        xn, wl, nullptr, out, nullptr, nullptr, nullptr, 4096, 32000, 1024);
}

// Round 9
// 1713.194 us; speedup vs baseline: 1.2702x; 1.0727x over previous
//
#include <hip/hip_runtime.h>

// ---------------------------------------------------------------------------
// Transformer (GateLoop-style) forward, MI355X/gfx950.  Round 9.
//  = round 8 + parameterized GEMM tile <EPI, BM, BN> (wave tile fixed 64x64,
//    waves = BM*BN/4096, proven 2-barrier loop + XOR swizzle):
//    - logits:  256x256, 16 waves (amortize K-step stall over 2x output)
//    - fused/W1: 256x128 (round-8 proven, keeps 2+ blocks/CU residency)
//    - Wo:      128x128 -> 256 blocks (was 128 = half GPU idle)
//    - W2:      split-K=2 (serial K-chain 64->32 steps) + combine kernel
// ---------------------------------------------------------------------------

typedef float fx4 __attribute__((ext_vector_type(4)));
typedef _Float16 f16x8 __attribute__((ext_vector_type(8)));
typedef _Float16 f16x4 __attribute__((ext_vector_type(4)));

#define AS1 __attribute__((address_space(1)))
#define AS3 __attribute__((address_space(3)))

// ---------------------------------------------------------------- transpose
__global__ __launch_bounds__(256) void transpose_f16_kernel(
    const float* __restrict__ in, _Float16* __restrict__ out,
    int K, int N, size_t ostride)
{
    __shared__ float tile[32][33];
    const int b = blockIdx.z;
    in  += (size_t)b * K * N;
    out += (size_t)b * ostride;
    const int k0 = blockIdx.x * 32, n0 = blockIdx.y * 32;
    const int tr = threadIdx.x >> 3;
    const int tc = (threadIdx.x & 7) * 4;
    fx4 v = *(const fx4*)&in[(size_t)(k0 + tr) * N + n0 + tc];
    tile[tr][tc + 0] = v[0]; tile[tr][tc + 1] = v[1];
    tile[tr][tc + 2] = v[2]; tile[tr][tc + 3] = v[3];
    __syncthreads();
    f16x4 o;
    #pragma unroll
    for (int e = 0; e < 4; ++e) o[e] = (_Float16)tile[tc + e][tr];
    *(f16x4*)&out[(size_t)(n0 + tr) * K + k0 + tc] = o;
}

// ---------------------------------------------------------------- embedding
__global__ __launch_bounds__(256) void embed_kernel(
    const int* __restrict__ tokens, const float* __restrict__ emb,
    float* __restrict__ x)
{
    const int row = blockIdx.x;
    const int t = tokens[row];
    const int c = threadIdx.x * 4;
    *(fx4*)&x[(size_t)row * 1024 + c] = *(const fx4*)&emb[(size_t)t * 1024 + c];
}

// ---------------------------------------------------------------- rms -> fp16
__global__ __launch_bounds__(256) void rms_f16_kernel(
    const float* __restrict__ x, const float* __restrict__ g,
    _Float16* __restrict__ outh)
{
    const int row = blockIdx.x;
    const int c = threadIdx.x * 4;
    fx4 v = *(const fx4*)&x[(size_t)row * 1024 + c];
    float ss = v[0]*v[0] + v[1]*v[1] + v[2]*v[2] + v[3]*v[3];
    #pragma unroll
    for (int off = 32; off > 0; off >>= 1) ss += __shfl_down(ss, off, 64);
    __shared__ float wsum[4];
    if ((threadIdx.x & 63) == 0) wsum[threadIdx.x >> 6] = ss;
    __syncthreads();
    const float nrm = sqrtf(wsum[0] + wsum[1] + wsum[2] + wsum[3]);
    const float scale = 32.0f / fmaxf(nrm, 1e-12f);
    fx4 gg = *(const fx4*)&g[c];
    f16x4 o;
    #pragma unroll
    for (int e = 0; e < 4; ++e) o[e] = (_Float16)(v[e] * scale * gg[e]);
    *(f16x4*)&outh[(size_t)row * 1024 + c] = o;
}

// ---------------------------------------------------------------- scan prep
__global__ __launch_bounds__(256) void prep_qkv_kernel(
    const float* __restrict__ qkv, float* __restrict__ qT, float* __restrict__ kvT)
{
    __shared__ float tq[32][33], tkv[32][33];
    const int n0 = blockIdx.x * 32, h0 = blockIdx.y * 32, b = blockIdx.z;
    const int tr = threadIdx.x >> 3;
    const int tc = (threadIdx.x & 7) * 4;
    const float* row = qkv + ((size_t)b * 2048 + n0 + tr) * 3072;
    fx4 qv = *(const fx4*)&row[h0 + tc];
    fx4 kv = *(const fx4*)&row[1024 + h0 + tc];
    fx4 vv = *(const fx4*)&row[2048 + h0 + tc];
    #pragma unroll
    for (int e = 0; e < 4; ++e) { tq[tr][tc + e] = qv[e]; tkv[tr][tc + e] = kv[e] * vv[e]; }
    __syncthreads();
    fx4 oq, okv;
    #pragma unroll
    for (int e = 0; e < 4; ++e) { oq[e] = tq[tc + e][tr]; okv[e] = tkv[tc + e][tr]; }
    const size_t ob = ((size_t)b * 1024 + h0 + tr) * 2048 + n0 + tc;
    *(fx4*)&qT[ob] = oq;
    *(fx4*)&kvT[ob] = okv;
}

__global__ __launch_bounds__(256) void prep_a_kernel(
    const float* __restrict__ al, float* __restrict__ aReT, float* __restrict__ aImT)
{
    __shared__ float tre[32][33], tim[32][33];
    const int n0 = blockIdx.x * 32, h0 = blockIdx.y * 32, b = blockIdx.z;
    const int tr = threadIdx.x >> 3;
    const int tcf = (threadIdx.x & 7) * 8;
    const float* row = al + ((size_t)b * 2048 + n0 + tr) * 2048 + 2 * h0;
    fx4 v0 = *(const fx4*)&row[tcf];
    fx4 v1 = *(const fx4*)&row[tcf + 4];
    #pragma unroll
    for (int p = 0; p < 4; ++p) {
        float re = (p < 2) ? v0[2 * p] : v1[2 * (p - 2)];
        float im = (p < 2) ? v0[2 * p + 1] : v1[2 * (p - 2) + 1];
        float r = sqrtf(re * re + im * im);
        float sg = 1.0f / (1.0f + expf(-r));
        float a_re, a_im;
        if (r > 0.0f) { float inv = sg / r; a_re = re * inv; a_im = im * inv; }
        else          { a_re = sg; a_im = 0.0f; }
        tre[tr][tcf / 2 + p] = a_re;
        tim[tr][tcf / 2 + p] = a_im;
    }
    __syncthreads();
    const int tc = (threadIdx.x & 7) * 4;
    fx4 ore, oim;
    #pragma unroll
    for (int e = 0; e < 4; ++e) { ore[e] = tre[tc + e][tr]; oim[e] = tim[tc + e][tr]; }
    const size_t ob = ((size_t)b * 1024 + h0 + tr) * 2048 + n0 + tc;
    *(fx4*)&aReT[ob] = ore;
    *(fx4*)&aImT[ob] = oim;
}

// ---------------------------------------------------------------- gate-loop scan
__device__ __forceinline__ int pidx(int i) { return i + (i >> 5); }

__global__ __launch_bounds__(256) void scanT_kernel(
    const float* __restrict__ kvT, const float* __restrict__ aReT,
    const float* __restrict__ aImT, const float* __restrict__ qT,
    float* __restrict__ yT)
{
    const int tid = threadIdx.x;
    const size_t base = (size_t)blockIdx.x * 2048;
    __shared__ float s_re[2048 + 64], s_im[2048 + 64], s_kv[2048 + 64];

    for (int i = tid; i < 512; i += 256) {
        fx4 kv = *(const fx4*)&kvT[base + i * 4];
        fx4 re = *(const fx4*)&aReT[base + i * 4];
        fx4 im = *(const fx4*)&aImT[base + i * 4];
        #pragma unroll
        for (int e = 0; e < 4; ++e) {
            const int j = pidx(i * 4 + e);
            s_kv[j] = kv[e]; s_re[j] = re[e]; s_im[j] = im[e];
        }
    }
    __syncthreads();

    for (int d = 0; d < 11; ++d) {
        const int half = 1 << d, stride = half << 1;
        const int npairs = 2048 >> (d + 1);
        for (int i = tid; i < npairs; i += 256) {
            const int rj = pidx(i * stride + stride - 1);
            const int lj = pidx(i * stride + stride - 1 - half);
            float lre = s_re[lj], lim = s_im[lj], lkv = s_kv[lj];
            float rre = s_re[rj], rim = s_im[rj], rkv = s_kv[rj];
            s_kv[rj] = rre * lkv + rkv;
            s_re[rj] = rre * lre - rim * lim;
            s_im[rj] = rre * lim + rim * lre;
        }
        __syncthreads();
    }
    for (int d = 9; d >= 0; --d) {
        const int w = 1 << d;
        const int nupd = (2048 >> (d + 1)) - 1;
        for (int t = tid; t < nupd; t += 256) {
            const int i = t + 1;
            const int rj = pidx((2 * i + 1) * w - 1);
            const int lj = pidx(2 * i * w - 1);
            float lre = s_re[lj], lim = s_im[lj], lkv = s_kv[lj];
            float rre = s_re[rj], rim = s_im[rj], rkv = s_kv[rj];
            s_kv[rj] = rre * lkv + rkv;
            s_re[rj] = rre * lre - rim * lim;
            s_im[rj] = rre * lim + rim * lre;
        }
        __syncthreads();
    }
    for (int i = tid; i < 512; i += 256) {
        fx4 q = *(const fx4*)&qT[base + i * 4];
        fx4 o;
        #pragma unroll
        for (int e = 0; e < 4; ++e) o[e] = q[e] * s_kv[pidx(i * 4 + e)];
        *(fx4*)&yT[base + i * 4] = o;
    }
}

// ---------------------------------------------------------------- gating
__global__ __launch_bounds__(256) void gate_kernel(
    const float* __restrict__ G, const float* __restrict__ yT,
    _Float16* __restrict__ gated)
{
    __shared__ float ty[32][33];
    const int n0 = blockIdx.x * 32, h0 = blockIdx.y * 32, b = blockIdx.z;
    const int tr = threadIdx.x >> 3;
    const int tc = (threadIdx.x & 7) * 4;
    fx4 yv = *(const fx4*)&yT[((size_t)b * 1024 + h0 + tr) * 2048 + n0 + tc];
    #pragma unroll
    for (int e = 0; e < 4; ++e) ty[tr][tc + e] = yv[e];
    __syncthreads();
    const size_t grow = ((size_t)b * 2048 + n0 + tr) * 1024 + h0 + tc;
    fx4 gv = *(const fx4*)&G[grow];
    f16x4 o;
    #pragma unroll
    for (int e = 0; e < 4; ++e) {
        const float s = gv[e] / (1.0f + expf(-gv[e]));   // silu
        o[e] = (_Float16)(s * ty[tc + e][tr]);
    }
    *(f16x4*)&gated[grow] = o;
}

// ---------------------------------------------------------------- W2 combine
// x += partial0 + partial1 + bias   (deterministic split-K reduction)
__global__ __launch_bounds__(256) void combine2_kernel(
    const float* __restrict__ p, const float* __restrict__ bias,
    float* __restrict__ x)
{
    const size_t i = ((size_t)blockIdx.x * 256 + threadIdx.x) * 4;
    fx4 a = *(const fx4*)&p[i];
    fx4 b = *(const fx4*)&p[i + (size_t)4096 * 1024];
    fx4 xx = *(const fx4*)&x[i];
    fx4 bb = *(const fx4*)&bias[(int)(i & 1023)];
    fx4 o;
    #pragma unroll
    for (int e = 0; e < 4; ++e) o[e] = xx[e] + (a[e] + b[e] + bb[e]);
    *(fx4*)&x[i] = o;
}

// ---------------------------------------------------------------- GEMM (fp16)
// C[M,N] = A[M,K](fp16) * Bt[N,K]^T(fp16), f32 accumulate.
// Tile BMxBN, wave tile 64x64 (4x4 fp32x4 acc), waves = BM*BN/4096,
// threads = BM*BN/64.  Single-buffer LDS, 2-barrier K-loop (proven),
// XOR swizzle on 16B granules (involution src+read; conflicts == 0 verified).
// K = loop extent, Kld = row stride (split-K: K < Kld).
// blockIdx.z = split-K slice: offsets A,Bt by z*K and Cf by z*M*N.
// EPI: 0=store f32, 2=Cf+=v, 4=Ch=f16(gelu(v+bias)),
//      6=fused routing (BN=128 grid): bn<24 -> Cf(qkv, ld 3072);
//        bn<40 -> Cf2+bias(al, ld 2048); else Cf3(G, ld 1024)
template<int EPI, int BM, int BN>
__global__ __launch_bounds__(BM * BN / 64) void gemm_kernel(
    const _Float16* __restrict__ A, const _Float16* __restrict__ Bt,
    const float* __restrict__ bias,
    float* __restrict__ Cf, float* __restrict__ Cf2, float* __restrict__ Cf3,
    _Float16* __restrict__ Ch,
    int M, int N, int K, int Kld)
{
    constexpr int THREADS = BM * BN / 64;
    constexpr int NW = BN / 64;                 // waves along N
    __shared__ __align__(16) _Float16 As[BM * 64];
    __shared__ __align__(16) _Float16 Bs[BN * 64];
    const int tid  = threadIdx.x;
    const int lane = tid & 63;
    const int wave = tid >> 6;
    const int bm = blockIdx.x, bn = blockIdx.y;
    const int bz = blockIdx.z;
    const int wm = (wave / NW) * 64;
    const int wn = (wave % NW) * 64;

    // split-K slice offsets (bz==0 -> no-op)
    A  += (size_t)bz * K;
    Bt += (size_t)bz * K;
    if (EPI == 0) Cf += (size_t)bz * M * N;

    fx4 acc[4][4] = {};

    const size_t aRow0 = (size_t)bm * BM;
    const size_t bRow0 = (size_t)bn * BN;

    for (int k0 = 0; k0 < K; k0 += 64) {
        constexpr int QA = BM * 8 / THREADS;
        #pragma unroll
        for (int q = 0; q < QA; ++q) {
            const int chunk = q * THREADS + tid;      // 0 .. BM*8-1
            const int row = chunk >> 3;
            const int slot = chunk & 7;
            const int gs = slot ^ (row & 7);          // pre-swizzled source slot
            const size_t aoff = (aRow0 + row) * (size_t)Kld + k0 + gs * 8;
            __builtin_amdgcn_global_load_lds((const AS1 void*)(A + aoff),
                (AS3 void*)((char*)As + chunk * 16), 16, 0, 0);
        }
        constexpr int QB = BN * 8 / THREADS;
        #pragma unroll
        for (int q = 0; q < QB; ++q) {
            const int chunk = q * THREADS + tid;      // 0 .. BN*8-1
            const int row = chunk >> 3;
            const int slot = chunk & 7;
            const int gs = slot ^ (row & 7);
            const size_t boff = (bRow0 + row) * (size_t)Kld + k0 + gs * 8;
            __builtin_amdgcn_global_load_lds((const AS1 void*)(Bt + boff),
                (AS3 void*)((char*)Bs + chunk * 16), 16, 0, 0);
        }
        __syncthreads();   // drains vmcnt(0): staged data visible

        #pragma unroll
        for (int kk = 0; kk < 2; ++kk) {
            const int sw = ((kk * 4 + (lane >> 4)) ^ (lane & 7)) * 16;
            f16x8 af[4], bf[4];
            #pragma unroll
            for (int i = 0; i < 4; ++i) {
                const int row = wm + i * 16 + (lane & 15);
                af[i] = *(const f16x8*)((const char*)As + row * 128 + sw);
            }
            #pragma unroll
            for (int j = 0; j < 4; ++j) {
                const int row = wn + j * 16 + (lane & 15);
                bf[j] = *(const f16x8*)((const char*)Bs + row * 128 + sw);
            }
            #pragma unroll
            for (int i = 0; i < 4; ++i)
                #pragma unroll
                for (int j = 0; j < 4; ++j)
                    acc[i][j] = __builtin_amdgcn_mfma_f32_16x16x32_f16(
                        af[i], bf[j], acc[i][j], 0, 0, 0);
        }
        __syncthreads();   // all reads done before next staging overwrites
    }

    // epilogue: C/D layout col=lane&15, row=(lane>>4)*4+r
    const int col_l = lane & 15, row_l = (lane >> 4) * 4;
    #pragma unroll
    for (int i = 0; i < 4; ++i) {
        #pragma unroll
        for (int j = 0; j < 4; ++j) {
            #pragma unroll
            for (int r = 0; r < 4; ++r) {
                const int row = bm * BM + wm + i * 16 + row_l + r;
                const int col = bn * BN + wn + j * 16 + col_l;
                const float v = acc[i][j][r];
                if (EPI == 0) {
                    Cf[(size_t)row * N + col] = v;
                } else if (EPI == 2) {
                    Cf[(size_t)row * N + col] += v;
                } else if (EPI == 4) {
                    const float t = v + bias[col];
                    const float gelu = 0.5f * t * (1.0f + erff(t * 0.70710678118654752f));
                    Ch[(size_t)row * N + col] = (_Float16)gelu;
                } else if (EPI == 6) {
                    if (bn < 24)      Cf [(size_t)row * 3072 + col] = v;
                    else if (bn < 40) Cf2[(size_t)row * 2048 + (col - 3072)] = v + bias[col - 3072];
                    else              Cf3[(size_t)row * 1024 + (col - 5120)] = v;
                }
            }
        }
    }
}

// ---------------------------------------------------------------- host
extern "C" void kernel_launch(void* const* d_in, const int* in_sizes, int n_in,
                              void* d_out, int out_size, void* d_ws, size_t ws_size,
                              hipStream_t stream)
{
    const int*   tokens = (const int*)d_in[0];
    const float* emb  = (const float*)d_in[1];
    const float* g1   = (const float*)d_in[2];
    const float* Wqkv = (const float*)d_in[3];
    const float* Wa   = (const float*)d_in[4];
    const float* ba   = (const float*)d_in[5];
    const float* Wg   = (const float*)d_in[6];
    const float* Wo   = (const float*)d_in[7];
    const float* g2   = (const float*)d_in[8];
    const float* W1   = (const float*)d_in[9];
    const float* b1   = (const float*)d_in[10];
    const float* W2   = (const float*)d_in[11];
    const float* b2   = (const float*)d_in[12];
    const float* gf   = (const float*)d_in[13];
    const float* Wl   = (const float*)d_in[14];
    float* out = (float*)d_out;

    char* ws = (char*)d_ws;
    size_t off = 0;
    auto take = [&](size_t bytes) {
        char* p = ws + off; off += (bytes + 255) & ~(size_t)255; return p;
    };

    // fp16 weights
    _Float16* wcat = (_Float16*)take((size_t)4 * 6144 * 1024 * 2);   // [Wqkv|Wa|Wg]^T per layer
    _Float16* wo   = (_Float16*)take((size_t)4 * 1024 * 1024 * 2);
    _Float16* w1   = (_Float16*)take((size_t)4 * 4096 * 1024 * 2);
    _Float16* w2   = (_Float16*)take((size_t)4 * 1024 * 4096 * 2);
    // region shared by 4x16MiB scan scratch (layers) and Wl fp16 (62.5MiB, end)
    char*     wlRegion = take((size_t)64 << 20);
    _Float16* wl   = (_Float16*)wlRegion;
    float*    x    = (float*)take((size_t)4096 * 1024 * 4);
    _Float16* xn   = (_Float16*)take((size_t)4096 * 1024 * 2);
    float*    qkvb = (float*)take((size_t)4096 * 3072 * 4);   // 48MiB (also hosts h fp16 33.5MiB)
    float*    alb  = (float*)take((size_t)4096 * 2048 * 4);   // 32MiB (al / yT+gated / W2 partials)
    float*    G    = (float*)take((size_t)4096 * 1024 * 4);   // 16MiB

    float* qT   = (float*)wlRegion;
    float* kvT  = (float*)(wlRegion + ((size_t)16 << 20));
    float* aReT = (float*)(wlRegion + ((size_t)32 << 20));
    float* aImT = (float*)(wlRegion + ((size_t)48 << 20));
    float*    yT    = alb;                                           // [0,16MiB)
    _Float16* gated = (_Float16*)((char*)alb + ((size_t)16 << 20));  // 8.4MiB
    _Float16* h     = (_Float16*)qkvb;                               // 33.5MiB
    float*    part  = alb;   // W2 split-K partials: 2 x 16MiB (al/yT/gated dead)

    const dim3 blk(256);

    // weight transposes (f32 [K][N] -> fp16 [N][K])
    transpose_f16_kernel<<<dim3(32,  96, 4), blk, 0, stream>>>(Wqkv, wcat,               1024, 3072, (size_t)6144 * 1024);
    transpose_f16_kernel<<<dim3(32,  64, 4), blk, 0, stream>>>(Wa,   wcat + 3072 * 1024, 1024, 2048, (size_t)6144 * 1024);
    transpose_f16_kernel<<<dim3(32,  32, 4), blk, 0, stream>>>(Wg,   wcat + 5120 * 1024, 1024, 1024, (size_t)6144 * 1024);
    transpose_f16_kernel<<<dim3(32,  32, 4), blk, 0, stream>>>(Wo,   wo,  1024, 1024, (size_t)1024 * 1024);
    transpose_f16_kernel<<<dim3(32, 128, 4), blk, 0, stream>>>(W1,   w1,  1024, 4096, (size_t)4096 * 1024);
    transpose_f16_kernel<<<dim3(128, 32, 4), blk, 0, stream>>>(W2,   w2,  4096, 1024, (size_t)1024 * 4096);

    embed_kernel<<<4096, blk, 0, stream>>>(tokens, emb, x);

    for (int i = 0; i < 4; ++i) {
        rms_f16_kernel<<<4096, blk, 0, stream>>>(x, g1 + i * 1024, xn);
        gemm_kernel<6, 256, 128><<<dim3(16, 48), dim3(512), 0, stream>>>(
            xn, wcat + (size_t)i * 6144 * 1024, ba + i * 2048,
            qkvb, alb, G, nullptr, 4096, 6144, 1024, 1024);
        prep_qkv_kernel<<<dim3(64, 32, 2), blk, 0, stream>>>(qkvb, qT, kvT);
        prep_a_kernel<<<dim3(64, 32, 2), blk, 0, stream>>>(alb, aReT, aImT);
        scanT_kernel<<<2048, blk, 0, stream>>>(kvT, aReT, aImT, qT, yT);
        gate_kernel<<<dim3(64, 32, 2), blk, 0, stream>>>(G, yT, gated);
        gemm_kernel<2, 128, 128><<<dim3(32, 8), blk, 0, stream>>>(
            gated, wo + (size_t)i * 1024 * 1024, nullptr,
            x, nullptr, nullptr, nullptr, 4096, 1024, 1024, 1024);
        rms_f16_kernel<<<4096, blk, 0, stream>>>(x, g2 + i * 1024, xn);
        gemm_kernel<4, 256, 128><<<dim3(16, 32), dim3(512), 0, stream>>>(
            xn, w1 + (size_t)i * 4096 * 1024, b1 + i * 4096,
            nullptr, nullptr, nullptr, h, 4096, 4096, 1024, 1024);
        // W2 split-K=2: partials then deterministic combine (+bias, += x)
        gemm_kernel<0, 256, 128><<<dim3(16, 8, 2), dim3(512), 0, stream>>>(
            h, w2 + (size_t)i * 1024 * 4096, nullptr,
            part, nullptr, nullptr, nullptr, 4096, 1024, 2048, 4096);
        combine2_kernel<<<4096, blk, 0, stream>>>(part, b2 + i * 1024, x);
    }

    // Wl transpose deferred: its region was scan scratch during the layers
    transpose_f16_kernel<<<dim3(32, 1000, 1), blk, 0, stream>>>(Wl, wl, 1024, 32000, 0);

    rms_f16_kernel<<<4096, blk, 0, stream>>>(x, gf, xn);
    gemm_kernel<0, 256, 256><<<dim3(16, 125), dim3(1024), 0, stream>>>(
        xn, wl, nullptr, out, nullptr, nullptr, nullptr, 4096, 32000, 1024, 1024);
}